// Round 5
// baseline (376.923 us; speedup 1.0000x reference)
//
#include <hip/hip_runtime.h>
#include <hip/hip_bf16.h>

// CausalMultiheadSelfAttention — B=2, S=2048, D=1024, H=16, dk=64
// R5: transposed-score flash attention: S^T = K·Q^T so softmax stats are
// per-lane (col=query); O^T = V^T·P^T keeps queries in lanes. 4 shfls/tile.
// Q pre-scaled by 0.125*log2e at RoPE -> exp2f. XOR-swizzled P LDS (8KB).

#define BATCH   2
#define SEQLEN  2048
#define DMODEL  1024
#define NHEADS  16
#define DK      64

typedef __attribute__((ext_vector_type(8))) short bf16x8;
typedef __attribute__((ext_vector_type(4))) short bf16x4;
typedef __attribute__((ext_vector_type(4))) float f32x4;

__device__ __forceinline__ void gload_lds16(const void* g, void* l) {
  __builtin_amdgcn_global_load_lds(
      (const __attribute__((address_space(1))) unsigned int*)g,
      (__attribute__((address_space(3))) unsigned int*)l, 16, 0, 0);
}

// ---------------- cast fp32 -> bf16: x (4M) + Wq/Wk/Wv/Wo (1M each) ----------
__global__ __launch_bounds__(256) void cast_all(
    const float* __restrict__ x,  const float* __restrict__ wq,
    const float* __restrict__ wk, const float* __restrict__ wv,
    const float* __restrict__ wo,
    __hip_bfloat16* __restrict__ xb,  __hip_bfloat16* __restrict__ wqb,
    __hip_bfloat16* __restrict__ wkb, __hip_bfloat16* __restrict__ wvb,
    __hip_bfloat16* __restrict__ wob) {
  const size_t MM = (size_t)1 << 20;
  size_t i = ((size_t)blockIdx.x * 256 + threadIdx.x) * 8;
  const float* src; __hip_bfloat16* dst; size_t off = i;
  if (i < 4 * MM)      { src = x;  dst = xb; }
  else if (i < 5 * MM) { src = wq; dst = wqb; off = i - 4 * MM; }
  else if (i < 6 * MM) { src = wk; dst = wkb; off = i - 5 * MM; }
  else if (i < 7 * MM) { src = wv; dst = wvb; off = i - 6 * MM; }
  else                 { src = wo; dst = wob; off = i - 7 * MM; }
  float4 a = *(const float4*)(src + off);
  float4 b = *(const float4*)(src + off + 4);
  __hip_bfloat16 t[8];
  t[0] = __float2bfloat16(a.x); t[1] = __float2bfloat16(a.y);
  t[2] = __float2bfloat16(a.z); t[3] = __float2bfloat16(a.w);
  t[4] = __float2bfloat16(b.x); t[5] = __float2bfloat16(b.y);
  t[6] = __float2bfloat16(b.z); t[7] = __float2bfloat16(b.w);
  *(bf16x8*)(dst + off) = *(const bf16x8*)t;
}

// ---------------- MFMA GEMM core: 128x128 tile, BK=32, 4 waves x 64x64 ------
__device__ __forceinline__ void gemm_core(
    const __hip_bfloat16* __restrict__ A, const __hip_bfloat16* __restrict__ W,
    int bm, int bn, int K, f32x4 (&acc)[4][4]) {
  __shared__ __hip_bfloat16 As[128 * 32];
  __shared__ __hip_bfloat16 Ws[128 * 32];
  const int tid  = threadIdx.x;
  const int wave = tid >> 6, lane = tid & 63;
  const int col  = lane & 15, quad = lane >> 4;
  const int wm   = (wave & 1) * 64, wn = (wave >> 1) * 64;
  const int srow = wave * 32;
  const int l4   = lane >> 2, sl = lane & 3;

  for (int k0 = 0; k0 < K; k0 += 32) {
#pragma unroll
    for (int c = 0; c < 2; ++c) {
      int r = srow + c * 16 + l4;
      int g = sl ^ (r & 3);
      gload_lds16(A + (size_t)(bm + r) * K + k0 + g * 8, &As[(srow + c * 16) * 32]);
      gload_lds16(W + (size_t)(bn + r) * K + k0 + g * 8, &Ws[(srow + c * 16) * 32]);
    }
    __syncthreads();
    bf16x8 af[4], bfr[4];
#pragma unroll
    for (int mt = 0; mt < 4; ++mt) {
      int r = wm + mt * 16 + col;
      af[mt] = *(const bf16x8*)&As[r * 32 + ((quad ^ (r & 3)) * 8)];
    }
#pragma unroll
    for (int nt = 0; nt < 4; ++nt) {
      int r = wn + nt * 16 + col;
      bfr[nt] = *(const bf16x8*)&Ws[r * 32 + ((quad ^ (r & 3)) * 8)];
    }
#pragma unroll
    for (int mt = 0; mt < 4; ++mt)
#pragma unroll
      for (int nt = 0; nt < 4; ++nt)
        acc[mt][nt] = __builtin_amdgcn_mfma_f32_16x16x32_bf16(af[mt], bfr[nt], acc[mt][nt], 0, 0, 0);
    __syncthreads();
  }
}

// ---------------- fused QKV GEMM (z: 0=Q, 1=K, 2=V-transposed) ---------------
__global__ __launch_bounds__(256) void mfma_qkv(
    const __hip_bfloat16* __restrict__ xb,
    const __hip_bfloat16* __restrict__ wqb,
    const __hip_bfloat16* __restrict__ wkb,
    const __hip_bfloat16* __restrict__ wvb,
    __hip_bfloat16* __restrict__ Qw,
    __hip_bfloat16* __restrict__ Kw,
    __hip_bfloat16* __restrict__ Vtw) {
  const int z = blockIdx.z;
  const __hip_bfloat16* W = (z == 0) ? wqb : (z == 1) ? wkb : wvb;
  const int bm = blockIdx.x * 128, bn = blockIdx.y * 128;
  f32x4 acc[4][4] = {};
  gemm_core(xb, W, bm, bn, DMODEL, acc);

  const int wave = threadIdx.x >> 6, lane = threadIdx.x & 63;
  const int col  = lane & 15, quad = lane >> 4;
  const int wm   = (wave & 1) * 64, wn = (wave >> 1) * 64;

  if (z < 2) {
    __hip_bfloat16* C = (z == 0) ? Qw : Kw;
#pragma unroll
    for (int mt = 0; mt < 4; ++mt)
#pragma unroll
      for (int nt = 0; nt < 4; ++nt) {
        int n = bn + wn + nt * 16 + col;
#pragma unroll
        for (int r = 0; r < 4; ++r) {
          int m = bm + wm + mt * 16 + quad * 4 + r;
          C[(size_t)m * DMODEL + n] = __float2bfloat16(acc[mt][nt][r]);
        }
      }
  } else {
#pragma unroll
    for (int mt = 0; mt < 4; ++mt)
#pragma unroll
      for (int nt = 0; nt < 4; ++nt) {
        int n  = bn + wn + nt * 16 + col;          // h = n>>6, dk = n&63
        int m0 = bm + wm + mt * 16 + quad * 4;     // b = m0>>11, s = m0&2047
        __hip_bfloat16 t[4];
#pragma unroll
        for (int r = 0; r < 4; ++r) t[r] = __float2bfloat16(acc[mt][nt][r]);
        size_t off = (((size_t)(m0 >> 11) * NHEADS + (n >> 6)) * DK + (n & 63)) * SEQLEN + (m0 & 2047);
        *(bf16x4*)(Vtw + off) = *(const bf16x4*)t;
      }
  }
}

// ---------------- out-projection GEMM: fp32 store to d_out -------------------
__global__ __launch_bounds__(256) void mfma_out(
    const __hip_bfloat16* __restrict__ Ow,
    const __hip_bfloat16* __restrict__ wob,
    float* __restrict__ out) {
  const int bm = blockIdx.x * 128, bn = blockIdx.y * 128;
  f32x4 acc[4][4] = {};
  gemm_core(Ow, wob, bm, bn, DMODEL, acc);
  const int wave = threadIdx.x >> 6, lane = threadIdx.x & 63;
  const int col  = lane & 15, quad = lane >> 4;
  const int wm   = (wave & 1) * 64, wn = (wave >> 1) * 64;
#pragma unroll
  for (int mt = 0; mt < 4; ++mt)
#pragma unroll
    for (int nt = 0; nt < 4; ++nt) {
      int n = bn + wn + nt * 16 + col;
#pragma unroll
      for (int r = 0; r < 4; ++r) {
        int m = bm + wm + mt * 16 + quad * 4 + r;
        out[(size_t)m * DMODEL + n] = acc[mt][nt][r];
      }
    }
}

// ---------------- RoPE; Q additionally scaled by 0.125*log2(e) ---------------
__global__ __launch_bounds__(256) void rope_kernel(
    __hip_bfloat16* __restrict__ Q,
    __hip_bfloat16* __restrict__ Kt,
    const int* __restrict__ pos, int npairs) {
  int idx = blockIdx.x * blockDim.x + threadIdx.x;
  if (idx >= npairs) return;
  int ip = idx & 511;
  int s  = (idx >> 9) & (SEQLEN - 1);
  int p  = ip & 31;
  float inv_freq = exp2f(-13.287712379549449f * ((float)(2 * p) / 64.0f));
  float ang = (float)pos[s] * inv_freq;
  float sn, cs;
  sincosf(ang, &sn, &cs);
  const float SCL = 0.18033688011112042f;  // 0.125 * log2(e)
  size_t off = (size_t)idx * 2;
  float qe = __bfloat162float(Q[off]), qo = __bfloat162float(Q[off + 1]);
  Q[off]     = __float2bfloat16((qe * cs - qo * sn) * SCL);
  Q[off + 1] = __float2bfloat16((qo * cs + qe * sn) * SCL);
  float ke = __bfloat162float(Kt[off]), ko = __bfloat162float(Kt[off + 1]);
  Kt[off]     = __float2bfloat16(ke * cs - ko * sn);
  Kt[off + 1] = __float2bfloat16(ko * cs + ke * sn);
}

// ---------------- transposed-score MFMA flash attention ----------------------
// Q,K,O: [b,s,1024] bf16. Vt: [b,h,64,2048] bf16.
// Block = 64 queries (4 waves x 16). Grid: (32 strips heavy-first, 32 bh).
// S^T = K·Q^T  (C: col=query, row=key). O^T = V^T·P^T (C: col=query, row=dv).
__global__ __launch_bounds__(256) void attn_mfma(
    const __hip_bfloat16* __restrict__ Q,
    const __hip_bfloat16* __restrict__ K,
    const __hip_bfloat16* __restrict__ Vt,
    __hip_bfloat16* __restrict__ O) {
  __shared__ __align__(16) __hip_bfloat16 Pl[4][16 * 64];  // per-wave P^T strip
  const int bh = blockIdx.y;
  const int b = bh >> 4, h = bh & 15;
  const int strip = 31 - (int)blockIdx.x;   // heavy blocks first
  const int wave = threadIdx.x >> 6;
  const int lane = threadIdx.x & 63;
  const int col = lane & 15;                // query within wave
  const int quad = lane >> 4;
  const int q0 = strip * 64 + wave * 16;    // wave's first query row
  const int cswz = col & 7;

  const size_t qkbase = ((size_t)b * SEQLEN) * DMODEL + (size_t)h * DK;
  const size_t vbase  = (size_t)bh * DK * SEQLEN;
  __hip_bfloat16* pl = &Pl[wave][0];

  // Q B-frag: B[n=col=query][k=kc*32+quad*8+j]
  bf16x8 qf[2];
#pragma unroll
  for (int kc = 0; kc < 2; ++kc)
    qf[kc] = *(const bf16x8*)(Q + qkbase + (size_t)(q0 + col) * DMODEL + kc * 32 + quad * 8);

  f32x4 acc[4] = {};               // O^T: row dv = dt*16+quad*4+r, col = query
  float m_i = -1e30f, l_i = 0.f;

  const int ntiles = strip + 1;
  for (int t = 0; t < ntiles; ++t) {
    const int j0 = t * 64;

    // ---- S^T = K·Q^T : 64 keys x 16 queries ----
    f32x4 s[4] = {};
#pragma unroll
    for (int kt = 0; kt < 4; ++kt)
#pragma unroll
      for (int kc = 0; kc < 2; ++kc) {
        bf16x8 kf = *(const bf16x8*)(K + qkbase +
            (size_t)(j0 + kt * 16 + col) * DMODEL + kc * 32 + quad * 8);
        s[kt] = __builtin_amdgcn_mfma_f32_16x16x32_bf16(kf, qf[kc], s[kt], 0, 0, 0);
      }

    // ---- causal mask on the diagonal tile only ----
    if (t == strip) {
      const int q = q0 + col;
#pragma unroll
      for (int kt = 0; kt < 4; ++kt)
#pragma unroll
        for (int r = 0; r < 4; ++r)
          if (j0 + kt * 16 + quad * 4 + r > q) s[kt][r] = -1e30f;
    }

    // ---- per-lane softmax stats (col = query), 4 shfls total ----
    float mx = m_i;
#pragma unroll
    for (int kt = 0; kt < 4; ++kt)
#pragma unroll
      for (int r = 0; r < 4; ++r) mx = fmaxf(mx, s[kt][r]);
    mx = fmaxf(mx, __shfl_xor(mx, 16, 64));
    mx = fmaxf(mx, __shfl_xor(mx, 32, 64));
    float alpha = exp2f(m_i - mx);
    m_i = mx;

    float rs = 0.f;
#pragma unroll
    for (int kt = 0; kt < 4; ++kt) {
      __hip_bfloat16 tp[4];
#pragma unroll
      for (int r = 0; r < 4; ++r) {
        float pv = exp2f(s[kt][r] - mx);
        rs += pv;
        tp[r] = __float2bfloat16(pv);
      }
      // P^T store: row=query(col), elements kt*16+quad*4..+3, XOR-swizzled 16B chunks
      int c = ((kt << 1) | (quad >> 1)) ^ cswz;
      *(bf16x4*)(pl + col * 64 + c * 8 + (quad & 1) * 4) = *(const bf16x4*)tp;
    }
    rs += __shfl_xor(rs, 16, 64);
    rs += __shfl_xor(rs, 32, 64);
    l_i = l_i * alpha + rs;
#pragma unroll
    for (int dt = 0; dt < 4; ++dt) acc[dt] *= alpha;

    // ---- O^T += V^T·P^T ----
#pragma unroll
    for (int jc = 0; jc < 2; ++jc) {
      int c = ((jc << 2) | quad) ^ cswz;
      bf16x8 pf = *(const bf16x8*)(pl + col * 64 + c * 8);
#pragma unroll
      for (int dt = 0; dt < 4; ++dt) {
        bf16x8 vf = *(const bf16x8*)(Vt + vbase +
            (size_t)(dt * 16 + col) * SEQLEN + j0 + jc * 32 + quad * 8);
        acc[dt] = __builtin_amdgcn_mfma_f32_16x16x32_bf16(vf, pf, acc[dt], 0, 0, 0);
      }
    }
  }

  // ---- epilogue: O[q][dv] = acc^T / l ----
  const float inv = 1.f / l_i;
  const size_t orow = qkbase + (size_t)(q0 + col) * DMODEL;
#pragma unroll
  for (int dt = 0; dt < 4; ++dt) {
    __hip_bfloat16 tp[4];
#pragma unroll
    for (int r = 0; r < 4; ++r) tp[r] = __float2bfloat16(acc[dt][r] * inv);
    *(bf16x4*)(O + orow + dt * 16 + quad * 4) = *(const bf16x4*)tp;
  }
}

// ---------------- launch -----------------------------------------------------
extern "C" void kernel_launch(void* const* d_in, const int* in_sizes, int n_in,
                              void* d_out, int out_size, void* d_ws, size_t ws_size,
                              hipStream_t stream) {
  const float* x  = (const float*)d_in[0];
  const float* Wq = (const float*)d_in[1];
  const float* Wk = (const float*)d_in[2];
  const float* Wv = (const float*)d_in[3];
  const float* Wo = (const float*)d_in[4];
  const int* pos  = (const int*)d_in[5];
  float* out = (float*)d_out;

  const size_t NELEM = (size_t)BATCH * SEQLEN * DMODEL;  // 4 Mi
  const size_t WELEM = (size_t)DMODEL * DMODEL;          // 1 Mi
  __hip_bfloat16* xb  = (__hip_bfloat16*)d_ws;
  __hip_bfloat16* Qw  = xb + NELEM;
  __hip_bfloat16* Kw  = Qw + NELEM;
  __hip_bfloat16* Vtw = Kw + NELEM;                      // [b][h][dk][s]
  __hip_bfloat16* wqb = Vtw + NELEM;
  __hip_bfloat16* wkb = wqb + WELEM;
  __hip_bfloat16* wvb = wkb + WELEM;
  __hip_bfloat16* wob = wvb + WELEM;
  __hip_bfloat16* Ow  = xb;   // alias: xb dead after QKV GEMM

  cast_all<<<4096, 256, 0, stream>>>(x, Wq, Wk, Wv, Wo, xb, wqb, wkb, wvb, wob);

  mfma_qkv<<<dim3(32, 8, 3), 256, 0, stream>>>(xb, wqb, wkb, wvb, Qw, Kw, Vtw);

  int npairs = BATCH * SEQLEN * (DMODEL / 2);
  rope_kernel<<<(npairs + 255) / 256, 256, 0, stream>>>(Qw, Kw, pos, npairs);

  attn_mfma<<<dim3(32, BATCH * NHEADS), 256, 0, stream>>>(Qw, Kw, Vtw, Ow);

  mfma_out<<<dim3(32, 8), 256, 0, stream>>>(Ow, wob, out);
}

// Round 6
// 371.565 us; speedup vs baseline: 1.0144x; 1.0144x over previous
//
#include <hip/hip_runtime.h>
#include <hip/hip_bf16.h>

// CausalMultiheadSelfAttention — B=2, S=2048, D=1024, H=16, dk=64
// R6: R5 + software-pipelined attention K-loop: double-buffered K frags in
// registers, V loads issued at tile top (consumed post-softmax), v_exp_f32.
// No barriers in the wave loop -> compiler emits fine-grained vmcnt waits.

#define BATCH   2
#define SEQLEN  2048
#define DMODEL  1024
#define NHEADS  16
#define DK      64

typedef __attribute__((ext_vector_type(8))) short bf16x8;
typedef __attribute__((ext_vector_type(4))) short bf16x4;
typedef __attribute__((ext_vector_type(4))) float f32x4;

__device__ __forceinline__ void gload_lds16(const void* g, void* l) {
  __builtin_amdgcn_global_load_lds(
      (const __attribute__((address_space(1))) unsigned int*)g,
      (__attribute__((address_space(3))) unsigned int*)l, 16, 0, 0);
}

__device__ __forceinline__ float fast_exp2(float x) {
#if __has_builtin(__builtin_amdgcn_exp2f)
  return __builtin_amdgcn_exp2f(x);
#else
  return exp2f(x);
#endif
}

// ---------------- cast fp32 -> bf16: x (4M) + Wq/Wk/Wv/Wo (1M each) ----------
__global__ __launch_bounds__(256) void cast_all(
    const float* __restrict__ x,  const float* __restrict__ wq,
    const float* __restrict__ wk, const float* __restrict__ wv,
    const float* __restrict__ wo,
    __hip_bfloat16* __restrict__ xb,  __hip_bfloat16* __restrict__ wqb,
    __hip_bfloat16* __restrict__ wkb, __hip_bfloat16* __restrict__ wvb,
    __hip_bfloat16* __restrict__ wob) {
  const size_t MM = (size_t)1 << 20;
  size_t i = ((size_t)blockIdx.x * 256 + threadIdx.x) * 8;
  const float* src; __hip_bfloat16* dst; size_t off = i;
  if (i < 4 * MM)      { src = x;  dst = xb; }
  else if (i < 5 * MM) { src = wq; dst = wqb; off = i - 4 * MM; }
  else if (i < 6 * MM) { src = wk; dst = wkb; off = i - 5 * MM; }
  else if (i < 7 * MM) { src = wv; dst = wvb; off = i - 6 * MM; }
  else                 { src = wo; dst = wob; off = i - 7 * MM; }
  float4 a = *(const float4*)(src + off);
  float4 b = *(const float4*)(src + off + 4);
  __hip_bfloat16 t[8];
  t[0] = __float2bfloat16(a.x); t[1] = __float2bfloat16(a.y);
  t[2] = __float2bfloat16(a.z); t[3] = __float2bfloat16(a.w);
  t[4] = __float2bfloat16(b.x); t[5] = __float2bfloat16(b.y);
  t[6] = __float2bfloat16(b.z); t[7] = __float2bfloat16(b.w);
  *(bf16x8*)(dst + off) = *(const bf16x8*)t;
}

// ---------------- MFMA GEMM core: 128x128 tile, BK=32, 4 waves x 64x64 ------
__device__ __forceinline__ void gemm_core(
    const __hip_bfloat16* __restrict__ A, const __hip_bfloat16* __restrict__ W,
    int bm, int bn, int K, f32x4 (&acc)[4][4]) {
  __shared__ __hip_bfloat16 As[128 * 32];
  __shared__ __hip_bfloat16 Ws[128 * 32];
  const int tid  = threadIdx.x;
  const int wave = tid >> 6, lane = tid & 63;
  const int col  = lane & 15, quad = lane >> 4;
  const int wm   = (wave & 1) * 64, wn = (wave >> 1) * 64;
  const int srow = wave * 32;
  const int l4   = lane >> 2, sl = lane & 3;

  for (int k0 = 0; k0 < K; k0 += 32) {
#pragma unroll
    for (int c = 0; c < 2; ++c) {
      int r = srow + c * 16 + l4;
      int g = sl ^ (r & 3);
      gload_lds16(A + (size_t)(bm + r) * K + k0 + g * 8, &As[(srow + c * 16) * 32]);
      gload_lds16(W + (size_t)(bn + r) * K + k0 + g * 8, &Ws[(srow + c * 16) * 32]);
    }
    __syncthreads();
    bf16x8 af[4], bfr[4];
#pragma unroll
    for (int mt = 0; mt < 4; ++mt) {
      int r = wm + mt * 16 + col;
      af[mt] = *(const bf16x8*)&As[r * 32 + ((quad ^ (r & 3)) * 8)];
    }
#pragma unroll
    for (int nt = 0; nt < 4; ++nt) {
      int r = wn + nt * 16 + col;
      bfr[nt] = *(const bf16x8*)&Ws[r * 32 + ((quad ^ (r & 3)) * 8)];
    }
#pragma unroll
    for (int mt = 0; mt < 4; ++mt)
#pragma unroll
      for (int nt = 0; nt < 4; ++nt)
        acc[mt][nt] = __builtin_amdgcn_mfma_f32_16x16x32_bf16(af[mt], bfr[nt], acc[mt][nt], 0, 0, 0);
    __syncthreads();
  }
}

// ---------------- fused QKV GEMM (z: 0=Q, 1=K, 2=V-transposed) ---------------
__global__ __launch_bounds__(256) void mfma_qkv(
    const __hip_bfloat16* __restrict__ xb,
    const __hip_bfloat16* __restrict__ wqb,
    const __hip_bfloat16* __restrict__ wkb,
    const __hip_bfloat16* __restrict__ wvb,
    __hip_bfloat16* __restrict__ Qw,
    __hip_bfloat16* __restrict__ Kw,
    __hip_bfloat16* __restrict__ Vtw) {
  const int z = blockIdx.z;
  const __hip_bfloat16* W = (z == 0) ? wqb : (z == 1) ? wkb : wvb;
  const int bm = blockIdx.x * 128, bn = blockIdx.y * 128;
  f32x4 acc[4][4] = {};
  gemm_core(xb, W, bm, bn, DMODEL, acc);

  const int wave = threadIdx.x >> 6, lane = threadIdx.x & 63;
  const int col  = lane & 15, quad = lane >> 4;
  const int wm   = (wave & 1) * 64, wn = (wave >> 1) * 64;

  if (z < 2) {
    __hip_bfloat16* C = (z == 0) ? Qw : Kw;
#pragma unroll
    for (int mt = 0; mt < 4; ++mt)
#pragma unroll
      for (int nt = 0; nt < 4; ++nt) {
        int n = bn + wn + nt * 16 + col;
#pragma unroll
        for (int r = 0; r < 4; ++r) {
          int m = bm + wm + mt * 16 + quad * 4 + r;
          C[(size_t)m * DMODEL + n] = __float2bfloat16(acc[mt][nt][r]);
        }
      }
  } else {
#pragma unroll
    for (int mt = 0; mt < 4; ++mt)
#pragma unroll
      for (int nt = 0; nt < 4; ++nt) {
        int n  = bn + wn + nt * 16 + col;          // h = n>>6, dk = n&63
        int m0 = bm + wm + mt * 16 + quad * 4;     // b = m0>>11, s = m0&2047
        __hip_bfloat16 t[4];
#pragma unroll
        for (int r = 0; r < 4; ++r) t[r] = __float2bfloat16(acc[mt][nt][r]);
        size_t off = (((size_t)(m0 >> 11) * NHEADS + (n >> 6)) * DK + (n & 63)) * SEQLEN + (m0 & 2047);
        *(bf16x4*)(Vtw + off) = *(const bf16x4*)t;
      }
  }
}

// ---------------- out-projection GEMM: fp32 store to d_out -------------------
__global__ __launch_bounds__(256) void mfma_out(
    const __hip_bfloat16* __restrict__ Ow,
    const __hip_bfloat16* __restrict__ wob,
    float* __restrict__ out) {
  const int bm = blockIdx.x * 128, bn = blockIdx.y * 128;
  f32x4 acc[4][4] = {};
  gemm_core(Ow, wob, bm, bn, DMODEL, acc);
  const int wave = threadIdx.x >> 6, lane = threadIdx.x & 63;
  const int col  = lane & 15, quad = lane >> 4;
  const int wm   = (wave & 1) * 64, wn = (wave >> 1) * 64;
#pragma unroll
  for (int mt = 0; mt < 4; ++mt)
#pragma unroll
    for (int nt = 0; nt < 4; ++nt) {
      int n = bn + wn + nt * 16 + col;
#pragma unroll
      for (int r = 0; r < 4; ++r) {
        int m = bm + wm + mt * 16 + quad * 4 + r;
        out[(size_t)m * DMODEL + n] = acc[mt][nt][r];
      }
    }
}

// ---------------- RoPE; Q additionally scaled by 0.125*log2(e) ---------------
__global__ __launch_bounds__(256) void rope_kernel(
    __hip_bfloat16* __restrict__ Q,
    __hip_bfloat16* __restrict__ Kt,
    const int* __restrict__ pos, int npairs) {
  int idx = blockIdx.x * blockDim.x + threadIdx.x;
  if (idx >= npairs) return;
  int ip = idx & 511;
  int s  = (idx >> 9) & (SEQLEN - 1);
  int p  = ip & 31;
  float inv_freq = exp2f(-13.287712379549449f * ((float)(2 * p) / 64.0f));
  float ang = (float)pos[s] * inv_freq;
  float sn, cs;
  sincosf(ang, &sn, &cs);
  const float SCL = 0.18033688011112042f;  // 0.125 * log2(e)
  size_t off = (size_t)idx * 2;
  float qe = __bfloat162float(Q[off]), qo = __bfloat162float(Q[off + 1]);
  Q[off]     = __float2bfloat16((qe * cs - qo * sn) * SCL);
  Q[off + 1] = __float2bfloat16((qo * cs + qe * sn) * SCL);
  float ke = __bfloat162float(Kt[off]), ko = __bfloat162float(Kt[off + 1]);
  Kt[off]     = __float2bfloat16(ke * cs - ko * sn);
  Kt[off + 1] = __float2bfloat16(ko * cs + ke * sn);
}

// ---------------- transposed-score MFMA flash attention (pipelined) ----------
// Q,K,O: [b,s,1024] bf16. Vt: [b,h,64,2048] bf16.
// Block = 64 queries (4 waves x 16). Grid: (32 strips heavy-first, 32 bh).
// S^T = K·Q^T (C: col=query, row=key). O^T = V^T·P^T (C: col=query, row=dv).
// Per-tile: V loads issued first, next-tile K prefetched into regs, softmax
// and P LDS round-trip run in the load shadow. No barriers -> fine vmcnt.
__global__ __launch_bounds__(256) void attn_mfma(
    const __hip_bfloat16* __restrict__ Q,
    const __hip_bfloat16* __restrict__ K,
    const __hip_bfloat16* __restrict__ Vt,
    __hip_bfloat16* __restrict__ O) {
  __shared__ __align__(16) __hip_bfloat16 Pl[4][16 * 64];  // per-wave P^T strip
  const int bh = blockIdx.y;
  const int b = bh >> 4, h = bh & 15;
  const int strip = 31 - (int)blockIdx.x;   // heavy blocks first
  const int wave = threadIdx.x >> 6;
  const int lane = threadIdx.x & 63;
  const int col = lane & 15;                // query within wave
  const int quad = lane >> 4;
  const int q0 = strip * 64 + wave * 16;    // wave's first query row
  const int cswz = col & 7;

  const size_t qkbase = ((size_t)b * SEQLEN) * DMODEL + (size_t)h * DK;
  const size_t vbase  = (size_t)bh * DK * SEQLEN;
  __hip_bfloat16* pl = &Pl[wave][0];
  const __hip_bfloat16* Kp = K + qkbase + (size_t)col * DMODEL + quad * 8;
  const __hip_bfloat16* Vp = Vt + vbase + (size_t)col * SEQLEN + quad * 8;

  // Q B-frag: B[n=col=query][k=kc*32+quad*8+j]
  bf16x8 qf[2];
#pragma unroll
  for (int kc = 0; kc < 2; ++kc)
    qf[kc] = *(const bf16x8*)(Q + qkbase + (size_t)(q0 + col) * DMODEL + kc * 32 + quad * 8);

  f32x4 acc[4] = {};               // O^T: row dv = dt*16+quad*4+r, col = query
  float m_i = -1e30f, l_i = 0.f;
  const int ntiles = strip + 1;

  bf16x8 ka[8], kb[8];
  // preload K tile 0 into ka
#pragma unroll
  for (int kt = 0; kt < 4; ++kt)
#pragma unroll
    for (int kc = 0; kc < 2; ++kc)
      ka[kt * 2 + kc] = *(const bf16x8*)(Kp + (size_t)(kt * 16) * DMODEL + kc * 32);

  auto do_tile = [&](int t, bf16x8 (&kf)[8], bf16x8 (&kn)[8], bool pre) {
    const int j0 = t * 64;

    // ---- V loads for this tile: consumed only after softmax (long shadow) ---
    bf16x8 vf[8];
#pragma unroll
    for (int jc = 0; jc < 2; ++jc)
#pragma unroll
      for (int dt = 0; dt < 4; ++dt)
        vf[jc * 4 + dt] = *(const bf16x8*)(Vp + (size_t)(dt * 16) * SEQLEN + j0 + jc * 32);

    // ---- prefetch next K tile into kn ----
    if (pre) {
#pragma unroll
      for (int kt = 0; kt < 4; ++kt)
#pragma unroll
        for (int kc = 0; kc < 2; ++kc)
          kn[kt * 2 + kc] = *(const bf16x8*)(Kp + (size_t)(j0 + 64 + kt * 16) * DMODEL + kc * 32);
    }

    // ---- S^T = K·Q^T : 64 keys x 16 queries ----
    f32x4 s[4] = {};
#pragma unroll
    for (int kt = 0; kt < 4; ++kt)
#pragma unroll
      for (int kc = 0; kc < 2; ++kc)
        s[kt] = __builtin_amdgcn_mfma_f32_16x16x32_bf16(kf[kt * 2 + kc], qf[kc], s[kt], 0, 0, 0);

    // ---- causal mask on the diagonal tile only ----
    if (t == strip) {
      const int q = q0 + col;
#pragma unroll
      for (int kt = 0; kt < 4; ++kt)
#pragma unroll
        for (int r = 0; r < 4; ++r)
          if (j0 + kt * 16 + quad * 4 + r > q) s[kt][r] = -1e30f;
    }

    // ---- per-lane softmax stats (col = query), 4 shfls total ----
    float mx = m_i;
#pragma unroll
    for (int kt = 0; kt < 4; ++kt)
#pragma unroll
      for (int r = 0; r < 4; ++r) mx = fmaxf(mx, s[kt][r]);
    mx = fmaxf(mx, __shfl_xor(mx, 16, 64));
    mx = fmaxf(mx, __shfl_xor(mx, 32, 64));
    float alpha = fast_exp2(m_i - mx);
    m_i = mx;

    float rs = 0.f;
#pragma unroll
    for (int kt = 0; kt < 4; ++kt) {
      __hip_bfloat16 tp[4];
#pragma unroll
      for (int r = 0; r < 4; ++r) {
        float pv = fast_exp2(s[kt][r] - mx);
        rs += pv;
        tp[r] = __float2bfloat16(pv);
      }
      int c = ((kt << 1) | (quad >> 1)) ^ cswz;
      *(bf16x4*)(pl + col * 64 + c * 8 + (quad & 1) * 4) = *(const bf16x4*)tp;
    }
    rs += __shfl_xor(rs, 16, 64);
    rs += __shfl_xor(rs, 32, 64);
    l_i = l_i * alpha + rs;
#pragma unroll
    for (int dt = 0; dt < 4; ++dt) acc[dt] *= alpha;

    // ---- O^T += V^T·P^T ----
#pragma unroll
    for (int jc = 0; jc < 2; ++jc) {
      int c = ((jc << 2) | quad) ^ cswz;
      bf16x8 pf = *(const bf16x8*)(pl + col * 64 + c * 8);
#pragma unroll
      for (int dt = 0; dt < 4; ++dt)
        acc[dt] = __builtin_amdgcn_mfma_f32_16x16x32_bf16(vf[jc * 4 + dt], pf, acc[dt], 0, 0, 0);
    }
  };

  int t = 0;
  while (true) {
    do_tile(t, ka, kb, t + 1 < ntiles);
    if (++t >= ntiles) break;
    do_tile(t, kb, ka, t + 1 < ntiles);
    if (++t >= ntiles) break;
  }

  // ---- epilogue: O[q][dv] = acc^T / l ----
  const float inv = 1.f / l_i;
  const size_t orow = qkbase + (size_t)(q0 + col) * DMODEL;
#pragma unroll
  for (int dt = 0; dt < 4; ++dt) {
    __hip_bfloat16 tp[4];
#pragma unroll
    for (int r = 0; r < 4; ++r) tp[r] = __float2bfloat16(acc[dt][r] * inv);
    *(bf16x4*)(O + orow + dt * 16 + quad * 4) = *(const bf16x4*)tp;
  }
}

// ---------------- launch -----------------------------------------------------
extern "C" void kernel_launch(void* const* d_in, const int* in_sizes, int n_in,
                              void* d_out, int out_size, void* d_ws, size_t ws_size,
                              hipStream_t stream) {
  const float* x  = (const float*)d_in[0];
  const float* Wq = (const float*)d_in[1];
  const float* Wk = (const float*)d_in[2];
  const float* Wv = (const float*)d_in[3];
  const float* Wo = (const float*)d_in[4];
  const int* pos  = (const int*)d_in[5];
  float* out = (float*)d_out;

  const size_t NELEM = (size_t)BATCH * SEQLEN * DMODEL;  // 4 Mi
  const size_t WELEM = (size_t)DMODEL * DMODEL;          // 1 Mi
  __hip_bfloat16* xb  = (__hip_bfloat16*)d_ws;
  __hip_bfloat16* Qw  = xb + NELEM;
  __hip_bfloat16* Kw  = Qw + NELEM;
  __hip_bfloat16* Vtw = Kw + NELEM;                      // [b][h][dk][s]
  __hip_bfloat16* wqb = Vtw + NELEM;
  __hip_bfloat16* wkb = wqb + WELEM;
  __hip_bfloat16* wvb = wkb + WELEM;
  __hip_bfloat16* wob = wvb + WELEM;
  __hip_bfloat16* Ow  = xb;   // alias: xb dead after QKV GEMM

  cast_all<<<4096, 256, 0, stream>>>(x, Wq, Wk, Wv, Wo, xb, wqb, wkb, wvb, wob);

  mfma_qkv<<<dim3(32, 8, 3), 256, 0, stream>>>(xb, wqb, wkb, wvb, Qw, Kw, Vtw);

  int npairs = BATCH * SEQLEN * (DMODEL / 2);
  rope_kernel<<<(npairs + 255) / 256, 256, 0, stream>>>(Qw, Kw, pos, npairs);

  attn_mfma<<<dim3(32, BATCH * NHEADS), 256, 0, stream>>>(Qw, Kw, Vtw, Ow);

  mfma_out<<<dim3(32, 8), 256, 0, stream>>>(Ow, wob, out);
}

// Round 7
// 214.789 us; speedup vs baseline: 1.7548x; 1.7299x over previous
//
#include <hip/hip_runtime.h>
#include <hip/hip_bf16.h>

// CausalMultiheadSelfAttention — B=2, S=2048, D=1024, H=16, dk=64
// R7: attention restructured GEMM-style: K/V tiles staged into LDS via
// coalesced global_load_lds (XOR-swizzled 16B chunks, conflict-free
// ds_read_b128 frags), double-buffered, shared by all 4 waves. Replaces the
// per-wave 16-line scattered gathers that R4-R6 all shared (invariant 229us).

#define BATCH   2
#define SEQLEN  2048
#define DMODEL  1024
#define NHEADS  16
#define DK      64

typedef __attribute__((ext_vector_type(8))) short bf16x8;
typedef __attribute__((ext_vector_type(4))) short bf16x4;
typedef __attribute__((ext_vector_type(4))) float f32x4;

__device__ __forceinline__ void gload_lds16(const void* g, void* l) {
  __builtin_amdgcn_global_load_lds(
      (const __attribute__((address_space(1))) unsigned int*)g,
      (__attribute__((address_space(3))) unsigned int*)l, 16, 0, 0);
}

__device__ __forceinline__ float fast_exp2(float x) {
#if __has_builtin(__builtin_amdgcn_exp2f)
  return __builtin_amdgcn_exp2f(x);
#else
  return exp2f(x);
#endif
}

// ---------------- cast fp32 -> bf16: x (4M) + Wq/Wk/Wv/Wo (1M each) ----------
__global__ __launch_bounds__(256) void cast_all(
    const float* __restrict__ x,  const float* __restrict__ wq,
    const float* __restrict__ wk, const float* __restrict__ wv,
    const float* __restrict__ wo,
    __hip_bfloat16* __restrict__ xb,  __hip_bfloat16* __restrict__ wqb,
    __hip_bfloat16* __restrict__ wkb, __hip_bfloat16* __restrict__ wvb,
    __hip_bfloat16* __restrict__ wob) {
  const size_t MM = (size_t)1 << 20;
  size_t i = ((size_t)blockIdx.x * 256 + threadIdx.x) * 8;
  const float* src; __hip_bfloat16* dst; size_t off = i;
  if (i < 4 * MM)      { src = x;  dst = xb; }
  else if (i < 5 * MM) { src = wq; dst = wqb; off = i - 4 * MM; }
  else if (i < 6 * MM) { src = wk; dst = wkb; off = i - 5 * MM; }
  else if (i < 7 * MM) { src = wv; dst = wvb; off = i - 6 * MM; }
  else                 { src = wo; dst = wob; off = i - 7 * MM; }
  float4 a = *(const float4*)(src + off);
  float4 b = *(const float4*)(src + off + 4);
  __hip_bfloat16 t[8];
  t[0] = __float2bfloat16(a.x); t[1] = __float2bfloat16(a.y);
  t[2] = __float2bfloat16(a.z); t[3] = __float2bfloat16(a.w);
  t[4] = __float2bfloat16(b.x); t[5] = __float2bfloat16(b.y);
  t[6] = __float2bfloat16(b.z); t[7] = __float2bfloat16(b.w);
  *(bf16x8*)(dst + off) = *(const bf16x8*)t;
}

// ---------------- MFMA GEMM core: 128x128 tile, BK=32, 4 waves x 64x64 ------
__device__ __forceinline__ void gemm_core(
    const __hip_bfloat16* __restrict__ A, const __hip_bfloat16* __restrict__ W,
    int bm, int bn, int K, f32x4 (&acc)[4][4]) {
  __shared__ __hip_bfloat16 As[128 * 32];
  __shared__ __hip_bfloat16 Ws[128 * 32];
  const int tid  = threadIdx.x;
  const int wave = tid >> 6, lane = tid & 63;
  const int col  = lane & 15, quad = lane >> 4;
  const int wm   = (wave & 1) * 64, wn = (wave >> 1) * 64;
  const int srow = wave * 32;
  const int l4   = lane >> 2, sl = lane & 3;

  for (int k0 = 0; k0 < K; k0 += 32) {
#pragma unroll
    for (int c = 0; c < 2; ++c) {
      int r = srow + c * 16 + l4;
      int g = sl ^ (r & 3);
      gload_lds16(A + (size_t)(bm + r) * K + k0 + g * 8, &As[(srow + c * 16) * 32]);
      gload_lds16(W + (size_t)(bn + r) * K + k0 + g * 8, &Ws[(srow + c * 16) * 32]);
    }
    __syncthreads();
    bf16x8 af[4], bfr[4];
#pragma unroll
    for (int mt = 0; mt < 4; ++mt) {
      int r = wm + mt * 16 + col;
      af[mt] = *(const bf16x8*)&As[r * 32 + ((quad ^ (r & 3)) * 8)];
    }
#pragma unroll
    for (int nt = 0; nt < 4; ++nt) {
      int r = wn + nt * 16 + col;
      bfr[nt] = *(const bf16x8*)&Ws[r * 32 + ((quad ^ (r & 3)) * 8)];
    }
#pragma unroll
    for (int mt = 0; mt < 4; ++mt)
#pragma unroll
      for (int nt = 0; nt < 4; ++nt)
        acc[mt][nt] = __builtin_amdgcn_mfma_f32_16x16x32_bf16(af[mt], bfr[nt], acc[mt][nt], 0, 0, 0);
    __syncthreads();
  }
}

// ---------------- fused QKV GEMM (z: 0=Q, 1=K, 2=V-transposed) ---------------
__global__ __launch_bounds__(256) void mfma_qkv(
    const __hip_bfloat16* __restrict__ xb,
    const __hip_bfloat16* __restrict__ wqb,
    const __hip_bfloat16* __restrict__ wkb,
    const __hip_bfloat16* __restrict__ wvb,
    __hip_bfloat16* __restrict__ Qw,
    __hip_bfloat16* __restrict__ Kw,
    __hip_bfloat16* __restrict__ Vtw) {
  const int z = blockIdx.z;
  const __hip_bfloat16* W = (z == 0) ? wqb : (z == 1) ? wkb : wvb;
  const int bm = blockIdx.x * 128, bn = blockIdx.y * 128;
  f32x4 acc[4][4] = {};
  gemm_core(xb, W, bm, bn, DMODEL, acc);

  const int wave = threadIdx.x >> 6, lane = threadIdx.x & 63;
  const int col  = lane & 15, quad = lane >> 4;
  const int wm   = (wave & 1) * 64, wn = (wave >> 1) * 64;

  if (z < 2) {
    __hip_bfloat16* C = (z == 0) ? Qw : Kw;
#pragma unroll
    for (int mt = 0; mt < 4; ++mt)
#pragma unroll
      for (int nt = 0; nt < 4; ++nt) {
        int n = bn + wn + nt * 16 + col;
#pragma unroll
        for (int r = 0; r < 4; ++r) {
          int m = bm + wm + mt * 16 + quad * 4 + r;
          C[(size_t)m * DMODEL + n] = __float2bfloat16(acc[mt][nt][r]);
        }
      }
  } else {
#pragma unroll
    for (int mt = 0; mt < 4; ++mt)
#pragma unroll
      for (int nt = 0; nt < 4; ++nt) {
        int n  = bn + wn + nt * 16 + col;          // h = n>>6, dk = n&63
        int m0 = bm + wm + mt * 16 + quad * 4;     // b = m0>>11, s = m0&2047
        __hip_bfloat16 t[4];
#pragma unroll
        for (int r = 0; r < 4; ++r) t[r] = __float2bfloat16(acc[mt][nt][r]);
        size_t off = (((size_t)(m0 >> 11) * NHEADS + (n >> 6)) * DK + (n & 63)) * SEQLEN + (m0 & 2047);
        *(bf16x4*)(Vtw + off) = *(const bf16x4*)t;
      }
  }
}

// ---------------- out-projection GEMM: fp32 store to d_out -------------------
__global__ __launch_bounds__(256) void mfma_out(
    const __hip_bfloat16* __restrict__ Ow,
    const __hip_bfloat16* __restrict__ wob,
    float* __restrict__ out) {
  const int bm = blockIdx.x * 128, bn = blockIdx.y * 128;
  f32x4 acc[4][4] = {};
  gemm_core(Ow, wob, bm, bn, DMODEL, acc);
  const int wave = threadIdx.x >> 6, lane = threadIdx.x & 63;
  const int col  = lane & 15, quad = lane >> 4;
  const int wm   = (wave & 1) * 64, wn = (wave >> 1) * 64;
#pragma unroll
  for (int mt = 0; mt < 4; ++mt)
#pragma unroll
    for (int nt = 0; nt < 4; ++nt) {
      int n = bn + wn + nt * 16 + col;
#pragma unroll
      for (int r = 0; r < 4; ++r) {
        int m = bm + wm + mt * 16 + quad * 4 + r;
        out[(size_t)m * DMODEL + n] = acc[mt][nt][r];
      }
    }
}

// ---------------- RoPE; Q additionally scaled by 0.125*log2(e) ---------------
__global__ __launch_bounds__(256) void rope_kernel(
    __hip_bfloat16* __restrict__ Q,
    __hip_bfloat16* __restrict__ Kt,
    const int* __restrict__ pos, int npairs) {
  int idx = blockIdx.x * blockDim.x + threadIdx.x;
  if (idx >= npairs) return;
  int ip = idx & 511;
  int s  = (idx >> 9) & (SEQLEN - 1);
  int p  = ip & 31;
  float inv_freq = exp2f(-13.287712379549449f * ((float)(2 * p) / 64.0f));
  float ang = (float)pos[s] * inv_freq;
  float sn, cs;
  sincosf(ang, &sn, &cs);
  const float SCL = 0.18033688011112042f;  // 0.125 * log2(e)
  size_t off = (size_t)idx * 2;
  float qe = __bfloat162float(Q[off]), qo = __bfloat162float(Q[off + 1]);
  Q[off]     = __float2bfloat16((qe * cs - qo * sn) * SCL);
  Q[off + 1] = __float2bfloat16((qo * cs + qe * sn) * SCL);
  float ke = __bfloat162float(Kt[off]), ko = __bfloat162float(Kt[off + 1]);
  Kt[off]     = __float2bfloat16(ke * cs - ko * sn);
  Kt[off + 1] = __float2bfloat16(ko * cs + ke * sn);
}

// ---------------- staged transposed-score MFMA flash attention ---------------
// Q,K,O: [b,s,1024] bf16. Vt: [b,h,64,2048] bf16.
// Block = 64 queries (4 waves x 16). Grid: (32 strips heavy-first, 32 bh).
// K/V tiles (64x64 bf16 = 8KB each) staged to LDS double-buffered via
// coalesced global_load_lds; 16B chunks XOR-swizzled by row so ds_read_b128
// fragment reads are conflict-free. One barrier per tile; stage(t+1) issued
// before compute(t) overlaps loads with MFMA+softmax (m97 structure).
__global__ __launch_bounds__(256) void attn_mfma(
    const __hip_bfloat16* __restrict__ Q,
    const __hip_bfloat16* __restrict__ K,
    const __hip_bfloat16* __restrict__ Vt,
    __hip_bfloat16* __restrict__ O) {
  __shared__ __align__(16) __hip_bfloat16 Ks[2][64 * 64];
  __shared__ __align__(16) __hip_bfloat16 Vs[2][64 * 64];
  __shared__ __align__(16) __hip_bfloat16 Pl[4][16 * 64];
  const int bh = blockIdx.y;
  const int b = bh >> 4, h = bh & 15;
  const int strip = 31 - (int)blockIdx.x;   // heavy blocks first
  const int wave = threadIdx.x >> 6;
  const int lane = threadIdx.x & 63;
  const int col = lane & 15;                // query within wave
  const int quad = lane >> 4;
  const int q0 = strip * 64 + wave * 16;
  const int cswz = col & 7;

  const size_t qkbase = ((size_t)b * SEQLEN) * DMODEL + (size_t)h * DK;
  const size_t vbase  = (size_t)bh * DK * SEQLEN;
  __hip_bfloat16* pl = &Pl[wave][0];

  // staging lane roles: 8 lanes x 16B cover one 128B row; 8 rows per instr
  const int srow = lane >> 3;     // 0..7: row within the 8-row group
  const int slot = lane & 7;      // 16B slot within the row

  // stage tile t (64 keys) into buf: K rows j0..j0+63, V rows dv 0..63
  auto stage = [&](int t, int buf) {
    const int j0 = t * 64;
#pragma unroll
    for (int c = 0; c < 2; ++c) {
      const int r = wave * 16 + c * 8 + srow;   // tile-local row 0..63
      const int g = slot ^ (r & 7);             // swizzled global 16B chunk
      gload_lds16(K + qkbase + (size_t)(j0 + r) * DMODEL + g * 8,
                  &Ks[buf][(wave * 16 + c * 8) * 64]);
      gload_lds16(Vt + vbase + (size_t)r * SEQLEN + j0 + g * 8,
                  &Vs[buf][(wave * 16 + c * 8) * 64]);
    }
  };

  // Q B-frag: B[n=col=query][k=kc*32+quad*8+j]
  bf16x8 qf[2];
#pragma unroll
  for (int kc = 0; kc < 2; ++kc)
    qf[kc] = *(const bf16x8*)(Q + qkbase + (size_t)(q0 + col) * DMODEL + kc * 32 + quad * 8);

  f32x4 acc[4] = {};               // O^T: row dv = dt*16+quad*4+r, col = query
  float m_i = -1e30f, l_i = 0.f;
  const int ntiles = strip + 1;

  stage(0, 0);
  __syncthreads();

  for (int t = 0; t < ntiles; ++t) {
    const int buf = t & 1;
    if (t + 1 < ntiles) stage(t + 1, buf ^ 1);
    const int j0 = t * 64;

    // ---- S^T = K·Q^T : 64 keys x 16 queries ----
    f32x4 s[4] = {};
#pragma unroll
    for (int kt = 0; kt < 4; ++kt) {
      const int row = kt * 16 + col;
#pragma unroll
      for (int kc = 0; kc < 2; ++kc) {
        bf16x8 kf = *(const bf16x8*)&Ks[buf][row * 64 + (((kc * 4 + quad) ^ cswz) * 8)];
        s[kt] = __builtin_amdgcn_mfma_f32_16x16x32_bf16(kf, qf[kc], s[kt], 0, 0, 0);
      }
    }

    // ---- causal mask on the diagonal tile only ----
    if (t == strip) {
      const int q = q0 + col;
#pragma unroll
      for (int kt = 0; kt < 4; ++kt)
#pragma unroll
        for (int r = 0; r < 4; ++r)
          if (j0 + kt * 16 + quad * 4 + r > q) s[kt][r] = -1e30f;
    }

    // ---- per-lane softmax stats (col = query), 4 shfls total ----
    float mx = m_i;
#pragma unroll
    for (int kt = 0; kt < 4; ++kt)
#pragma unroll
      for (int r = 0; r < 4; ++r) mx = fmaxf(mx, s[kt][r]);
    mx = fmaxf(mx, __shfl_xor(mx, 16, 64));
    mx = fmaxf(mx, __shfl_xor(mx, 32, 64));
    float alpha = fast_exp2(m_i - mx);
    m_i = mx;

    float rs = 0.f;
#pragma unroll
    for (int kt = 0; kt < 4; ++kt) {
      __hip_bfloat16 tp[4];
#pragma unroll
      for (int r = 0; r < 4; ++r) {
        float pv = fast_exp2(s[kt][r] - mx);
        rs += pv;
        tp[r] = __float2bfloat16(pv);
      }
      int c = ((kt << 1) | (quad >> 1)) ^ cswz;
      *(bf16x4*)(pl + col * 64 + c * 8 + (quad & 1) * 4) = *(const bf16x4*)tp;
    }
    rs += __shfl_xor(rs, 16, 64);
    rs += __shfl_xor(rs, 32, 64);
    l_i = l_i * alpha + rs;
#pragma unroll
    for (int dt = 0; dt < 4; ++dt) acc[dt] *= alpha;

    // ---- O^T += V^T·P^T ----
#pragma unroll
    for (int jc = 0; jc < 2; ++jc) {
      int c = ((jc << 2) | quad) ^ cswz;
      bf16x8 pf = *(const bf16x8*)(pl + col * 64 + c * 8);
#pragma unroll
      for (int dt = 0; dt < 4; ++dt) {
        const int dv = dt * 16 + col;
        bf16x8 vf = *(const bf16x8*)&Vs[buf][dv * 64 + (((jc * 4 + quad) ^ cswz) * 8)];
        acc[dt] = __builtin_amdgcn_mfma_f32_16x16x32_bf16(vf, pf, acc[dt], 0, 0, 0);
      }
    }

    __syncthreads();   // stage(t+1) drained; all waves done reading buf
  }

  // ---- epilogue: O[q][dv] = acc^T / l ----
  const float inv = 1.f / l_i;
  const size_t orow = qkbase + (size_t)(q0 + col) * DMODEL;
#pragma unroll
  for (int dt = 0; dt < 4; ++dt) {
    __hip_bfloat16 tp[4];
#pragma unroll
    for (int r = 0; r < 4; ++r) tp[r] = __float2bfloat16(acc[dt][r] * inv);
    *(bf16x4*)(O + orow + dt * 16 + quad * 4) = *(const bf16x4*)tp;
  }
}

// ---------------- launch -----------------------------------------------------
extern "C" void kernel_launch(void* const* d_in, const int* in_sizes, int n_in,
                              void* d_out, int out_size, void* d_ws, size_t ws_size,
                              hipStream_t stream) {
  const float* x  = (const float*)d_in[0];
  const float* Wq = (const float*)d_in[1];
  const float* Wk = (const float*)d_in[2];
  const float* Wv = (const float*)d_in[3];
  const float* Wo = (const float*)d_in[4];
  const int* pos  = (const int*)d_in[5];
  float* out = (float*)d_out;

  const size_t NELEM = (size_t)BATCH * SEQLEN * DMODEL;  // 4 Mi
  const size_t WELEM = (size_t)DMODEL * DMODEL;          // 1 Mi
  __hip_bfloat16* xb  = (__hip_bfloat16*)d_ws;
  __hip_bfloat16* Qw  = xb + NELEM;
  __hip_bfloat16* Kw  = Qw + NELEM;
  __hip_bfloat16* Vtw = Kw + NELEM;                      // [b][h][dk][s]
  __hip_bfloat16* wqb = Vtw + NELEM;
  __hip_bfloat16* wkb = wqb + WELEM;
  __hip_bfloat16* wvb = wkb + WELEM;
  __hip_bfloat16* wob = wvb + WELEM;
  __hip_bfloat16* Ow  = xb;   // alias: xb dead after QKV GEMM

  cast_all<<<4096, 256, 0, stream>>>(x, Wq, Wk, Wv, Wo, xb, wqb, wkb, wvb, wob);

  mfma_qkv<<<dim3(32, 8, 3), 256, 0, stream>>>(xb, wqb, wkb, wvb, Qw, Kw, Vtw);

  int npairs = BATCH * SEQLEN * (DMODEL / 2);
  rope_kernel<<<(npairs + 255) / 256, 256, 0, stream>>>(Qw, Kw, pos, npairs);

  attn_mfma<<<dim3(32, BATCH * NHEADS), 256, 0, stream>>>(Qw, Kw, Vtw, Ow);

  mfma_out<<<dim3(32, 8), 256, 0, stream>>>(Ow, wob, out);
}